// Round 9
// baseline (1020.229 us; speedup 1.0000x reference)
//
#include <hip/hip_runtime.h>
#include <hip/hip_bf16.h>
#include <cfloat>

// Problem constants
#define BB 8
#define TT 2048
#define CC 512
#define NNODE 1024

#define GAP_MARGIN 1e-3f  // screening margin (~1600x bf16-split-chain decision noise)
#define MAXC 6            // max rival candidates per flagged token (fits 8-slot clist)

typedef float f32x4 __attribute__((ext_vector_type(4)));
typedef short bf16x8 __attribute__((ext_vector_type(8)));
typedef float float4v __attribute__((ext_vector_type(4)));

// ---------------------------------------------------------------------------
// Order-preserving f32 <-> u32 key
// ---------------------------------------------------------------------------
__device__ __forceinline__ unsigned fkey(float v) {
  unsigned u = __float_as_uint(v);
  return (u & 0x80000000u) ? ~u : (u | 0x80000000u);
}
__device__ __forceinline__ float fdec(unsigned k) {
  unsigned u = (k & 0x80000000u) ? (k & 0x7FFFFFFFu) : ~k;
  return __uint_as_float(u);
}

// bf16 round-to-nearest-even helpers (bit-level)
__device__ __forceinline__ unsigned short bf16_rn(float f) {
  unsigned u = __float_as_uint(f);
  u += 0x7FFFu + ((u >> 16) & 1u);
  return (unsigned short)(u >> 16);
}
__device__ __forceinline__ float bf16_tof(unsigned short h) {
  return __uint_as_float(((unsigned)h) << 16);
}

// ---------------------------------------------------------------------------
// MFMA GEMM: C[m,n] = alpha*sum_k A[m,k]*B(k,n) (+bias), f32 in/out.
//   SPLIT: bf16-split (hh+hl+lh); TRANS_B: B is [N][K] row-major.
// 128x128 tile, BK=32, 256 threads (4 waves, 2x2), 16x16x32 frags.
// ---------------------------------------------------------------------------
template <bool SPLIT, bool TRANS_B, int BIAS_MODE>
__global__ __launch_bounds__(256) void mfma_gemm(
    const float* __restrict__ A, const float* __restrict__ Bm,
    float* __restrict__ Cp, const float* __restrict__ bias,
    int K, int lda, int ldb, int ldc,
    long long sA, long long sB, long long sC, float alpha) {
  __shared__ unsigned short Ah[128][40], Al[128][40], Bh[128][40], Bl[128][40];

  const int b = blockIdx.z;
  A += (long long)b * sA;
  Bm += (long long)b * sB;
  const int m0 = blockIdx.y * 128;
  const int n0 = blockIdx.x * 128;
  const int tid = threadIdx.x;
  const int l = tid & 63;
  const int wid = tid >> 6;
  const int wy = wid >> 1, wx = wid & 1;
  const int lrow = l & 15, lkb = (l >> 4) * 8;

  f32x4 acc[4][4] = {};

  for (int k0 = 0; k0 < K; k0 += 32) {
    {
      int r = tid >> 3, c = (tid & 7) * 4;
#pragma unroll
      for (int p = 0; p < 4; ++p, r += 32) {
        float4v v = *(const float4v*)(A + (long long)(m0 + r) * lda + k0 + c);
#pragma unroll
        for (int i = 0; i < 4; ++i) {
          unsigned short h = bf16_rn(v[i]);
          Ah[r][c + i] = h;
          if (SPLIT) Al[r][c + i] = bf16_rn(v[i] - bf16_tof(h));
        }
      }
    }
    if (TRANS_B) {
      int r = tid >> 3, c = (tid & 7) * 4;
#pragma unroll
      for (int p = 0; p < 4; ++p, r += 32) {
        float4v v = *(const float4v*)(Bm + (long long)(n0 + r) * ldb + k0 + c);
#pragma unroll
        for (int i = 0; i < 4; ++i) {
          unsigned short h = bf16_rn(v[i]);
          Bh[r][c + i] = h;
          if (SPLIT) Bl[r][c + i] = bf16_rn(v[i] - bf16_tof(h));
        }
      }
    } else {
      int kk = tid >> 5, c = (tid & 31) * 4;
#pragma unroll
      for (int p = 0; p < 4; ++p, kk += 8) {
        float4v v = *(const float4v*)(Bm + (long long)(k0 + kk) * ldb + n0 + c);
#pragma unroll
        for (int i = 0; i < 4; ++i) {
          unsigned short h = bf16_rn(v[i]);
          Bh[c + i][kk] = h;
          if (SPLIT) Bl[c + i][kk] = bf16_rn(v[i] - bf16_tof(h));
        }
      }
    }
    __syncthreads();

    bf16x8 ah[4], bh[4], al[4], bl[4];
#pragma unroll
    for (int mf = 0; mf < 4; ++mf) {
      ah[mf] = *(const bf16x8*)&Ah[wy * 64 + mf * 16 + lrow][lkb];
      if (SPLIT) al[mf] = *(const bf16x8*)&Al[wy * 64 + mf * 16 + lrow][lkb];
    }
#pragma unroll
    for (int nf = 0; nf < 4; ++nf) {
      bh[nf] = *(const bf16x8*)&Bh[wx * 64 + nf * 16 + lrow][lkb];
      if (SPLIT) bl[nf] = *(const bf16x8*)&Bl[wx * 64 + nf * 16 + lrow][lkb];
    }
#pragma unroll
    for (int mf = 0; mf < 4; ++mf)
#pragma unroll
      for (int nf = 0; nf < 4; ++nf) {
        acc[mf][nf] =
            __builtin_amdgcn_mfma_f32_16x16x32_bf16(ah[mf], bh[nf], acc[mf][nf], 0, 0, 0);
        if (SPLIT) {
          acc[mf][nf] =
              __builtin_amdgcn_mfma_f32_16x16x32_bf16(ah[mf], bl[nf], acc[mf][nf], 0, 0, 0);
          acc[mf][nf] =
              __builtin_amdgcn_mfma_f32_16x16x32_bf16(al[mf], bh[nf], acc[mf][nf], 0, 0, 0);
        }
      }
    __syncthreads();
  }

#pragma unroll
  for (int mf = 0; mf < 4; ++mf)
#pragma unroll
    for (int r = 0; r < 4; ++r) {
      int m = m0 + wy * 64 + mf * 16 + (l >> 4) * 4 + r;
#pragma unroll
      for (int nf = 0; nf < 4; ++nf) {
        int n = n0 + wx * 64 + nf * 16 + lrow;
        float v = acc[mf][nf][r] * alpha;
        if (BIAS_MODE == 1) v += bias[m];
        if (BIAS_MODE == 2) v += bias[n];
        Cp[sC * b + (long long)m * ldc + n] = v;
      }
    }
}

// ---------------------------------------------------------------------------
// Fused k (bf16-split, f32 out) + v (plain bf16, bf16 out) projection.
// ---------------------------------------------------------------------------
__global__ __launch_bounds__(256) void mfma_kv(
    const float* __restrict__ x, const float* __restrict__ Wk,
    const float* __restrict__ Wv, float* __restrict__ kout,
    unsigned short* __restrict__ vout) {
  __shared__ unsigned short Ah[128][40], Al[128][40], Bkh[128][40], Bkl[128][40],
      Bvh[128][40];

  const int b = blockIdx.z;
  const float* A = x + (size_t)b * TT * CC;
  const int m0 = blockIdx.y * 128;  // tokens
  const int n0 = blockIdx.x * 128;  // out dim
  const int tid = threadIdx.x;
  const int l = tid & 63;
  const int wid = tid >> 6;
  const int wy = wid >> 1, wx = wid & 1;
  const int lrow = l & 15, lkb = (l >> 4) * 8;

  f32x4 acck[4][4] = {}, accv[4][4] = {};

  for (int k0 = 0; k0 < CC; k0 += 32) {
    {
      int r = tid >> 3, c = (tid & 7) * 4;
#pragma unroll
      for (int p = 0; p < 4; ++p, r += 32) {
        float4v v = *(const float4v*)(A + (size_t)(m0 + r) * CC + k0 + c);
        float4v wk = *(const float4v*)(Wk + (size_t)(n0 + r) * CC + k0 + c);
        float4v wv = *(const float4v*)(Wv + (size_t)(n0 + r) * CC + k0 + c);
#pragma unroll
        for (int i = 0; i < 4; ++i) {
          unsigned short h = bf16_rn(v[i]);
          Ah[r][c + i] = h;
          Al[r][c + i] = bf16_rn(v[i] - bf16_tof(h));
          unsigned short hk = bf16_rn(wk[i]);
          Bkh[r][c + i] = hk;
          Bkl[r][c + i] = bf16_rn(wk[i] - bf16_tof(hk));
          Bvh[r][c + i] = bf16_rn(wv[i]);
        }
      }
    }
    __syncthreads();

    bf16x8 ah[4], al[4], bkh[4], bkl[4], bvh[4];
#pragma unroll
    for (int mf = 0; mf < 4; ++mf) {
      ah[mf] = *(const bf16x8*)&Ah[wy * 64 + mf * 16 + lrow][lkb];
      al[mf] = *(const bf16x8*)&Al[wy * 64 + mf * 16 + lrow][lkb];
    }
#pragma unroll
    for (int nf = 0; nf < 4; ++nf) {
      bkh[nf] = *(const bf16x8*)&Bkh[wx * 64 + nf * 16 + lrow][lkb];
      bkl[nf] = *(const bf16x8*)&Bkl[wx * 64 + nf * 16 + lrow][lkb];
      bvh[nf] = *(const bf16x8*)&Bvh[wx * 64 + nf * 16 + lrow][lkb];
    }
#pragma unroll
    for (int mf = 0; mf < 4; ++mf)
#pragma unroll
      for (int nf = 0; nf < 4; ++nf) {
        acck[mf][nf] =
            __builtin_amdgcn_mfma_f32_16x16x32_bf16(ah[mf], bkh[nf], acck[mf][nf], 0, 0, 0);
        acck[mf][nf] =
            __builtin_amdgcn_mfma_f32_16x16x32_bf16(ah[mf], bkl[nf], acck[mf][nf], 0, 0, 0);
        acck[mf][nf] =
            __builtin_amdgcn_mfma_f32_16x16x32_bf16(al[mf], bkh[nf], acck[mf][nf], 0, 0, 0);
        accv[mf][nf] =
            __builtin_amdgcn_mfma_f32_16x16x32_bf16(ah[mf], bvh[nf], accv[mf][nf], 0, 0, 0);
      }
    __syncthreads();
  }

#pragma unroll
  for (int mf = 0; mf < 4; ++mf)
#pragma unroll
    for (int r = 0; r < 4; ++r) {
      int m = m0 + wy * 64 + mf * 16 + (l >> 4) * 4 + r;
#pragma unroll
      for (int nf = 0; nf < 4; ++nf) {
        int n = n0 + wx * 64 + nf * 16 + lrow;
        size_t off = ((size_t)b * TT + m) * CC + n;
        kout[off] = acck[mf][nf][r];
        vout[off] = bf16_rn(accv[mf][nf][r]);
      }
    }
}

// ---------------------------------------------------------------------------
// sim (bf16-split MFMA, no store) + per-block per-token top-3 candidates.
// ---------------------------------------------------------------------------
__global__ __launch_bounds__(256) void mfma_sim_top3(
    const float* __restrict__ q, const float* __restrict__ kb,
    unsigned long long* __restrict__ cand1, unsigned long long* __restrict__ cand2,
    unsigned long long* __restrict__ cand3) {
  __shared__ unsigned short Ah[128][40], Al[128][40], Bh[128][40], Bl[128][40];
  __shared__ unsigned long long c1[128], c2[128], c3[128];

  const int b = blockIdx.z;
  const float* A = q + (size_t)b * NNODE * CC;
  const float* Bm = kb + (size_t)b * TT * CC;
  const int n0 = blockIdx.y * 128;  // nodes
  const int t0 = blockIdx.x * 128;  // tokens
  const int tid = threadIdx.x;
  const int l = tid & 63;
  const int wid = tid >> 6;
  const int wy = wid >> 1, wx = wid & 1;
  const int lrow = l & 15, lkb = (l >> 4) * 8;

  if (tid < 128) { c1[tid] = 0ULL; c2[tid] = 0ULL; c3[tid] = 0ULL; }

  f32x4 acc[4][4] = {};

  for (int k0 = 0; k0 < CC; k0 += 32) {
    {
      int r = tid >> 3, c = (tid & 7) * 4;
#pragma unroll
      for (int p = 0; p < 4; ++p, r += 32) {
        float4v v = *(const float4v*)(A + (size_t)(n0 + r) * CC + k0 + c);
        float4v w = *(const float4v*)(Bm + (size_t)(t0 + r) * CC + k0 + c);
#pragma unroll
        for (int i = 0; i < 4; ++i) {
          unsigned short h = bf16_rn(v[i]);
          Ah[r][c + i] = h;
          Al[r][c + i] = bf16_rn(v[i] - bf16_tof(h));
          unsigned short hb = bf16_rn(w[i]);
          Bh[r][c + i] = hb;
          Bl[r][c + i] = bf16_rn(w[i] - bf16_tof(hb));
        }
      }
    }
    __syncthreads();

    bf16x8 ah[4], al[4], bh[4], bl[4];
#pragma unroll
    for (int mf = 0; mf < 4; ++mf) {
      ah[mf] = *(const bf16x8*)&Ah[wy * 64 + mf * 16 + lrow][lkb];
      al[mf] = *(const bf16x8*)&Al[wy * 64 + mf * 16 + lrow][lkb];
    }
#pragma unroll
    for (int nf = 0; nf < 4; ++nf) {
      bh[nf] = *(const bf16x8*)&Bh[wx * 64 + nf * 16 + lrow][lkb];
      bl[nf] = *(const bf16x8*)&Bl[wx * 64 + nf * 16 + lrow][lkb];
    }
#pragma unroll
    for (int mf = 0; mf < 4; ++mf)
#pragma unroll
      for (int nf = 0; nf < 4; ++nf) {
        acc[mf][nf] =
            __builtin_amdgcn_mfma_f32_16x16x32_bf16(ah[mf], bh[nf], acc[mf][nf], 0, 0, 0);
        acc[mf][nf] =
            __builtin_amdgcn_mfma_f32_16x16x32_bf16(ah[mf], bl[nf], acc[mf][nf], 0, 0, 0);
        acc[mf][nf] =
            __builtin_amdgcn_mfma_f32_16x16x32_bf16(al[mf], bh[nf], acc[mf][nf], 0, 0, 0);
      }
    __syncthreads();
  }

  const float scl = 0.04419417382415922f;
#pragma unroll
  for (int nf = 0; nf < 4; ++nf) {
    int tcol = wx * 64 + nf * 16 + lrow;
    unsigned long long m = 0ULL;
#pragma unroll
    for (int mf = 0; mf < 4; ++mf)
#pragma unroll
      for (int r = 0; r < 4; ++r) {
        unsigned node = (unsigned)(n0 + wy * 64 + mf * 16 + (l >> 4) * 4 + r);
        unsigned long long pk =
            ((unsigned long long)fkey(acc[mf][nf][r] * scl) << 32) | node;
        if (pk > m) m = pk;
      }
    atomicMax(&c1[tcol], m);
  }
  __syncthreads();
#pragma unroll
  for (int nf = 0; nf < 4; ++nf) {
    int tcol = wx * 64 + nf * 16 + lrow;
    unsigned w1 = (unsigned)c1[tcol];
    unsigned long long m = 0ULL;
#pragma unroll
    for (int mf = 0; mf < 4; ++mf)
#pragma unroll
      for (int r = 0; r < 4; ++r) {
        unsigned node = (unsigned)(n0 + wy * 64 + mf * 16 + (l >> 4) * 4 + r);
        if (node == w1) continue;
        unsigned long long pk =
            ((unsigned long long)fkey(acc[mf][nf][r] * scl) << 32) | node;
        if (pk > m) m = pk;
      }
    if (m) atomicMax(&c2[tcol], m);
  }
  __syncthreads();
#pragma unroll
  for (int nf = 0; nf < 4; ++nf) {
    int tcol = wx * 64 + nf * 16 + lrow;
    unsigned w1 = (unsigned)c1[tcol];
    unsigned w2 = (unsigned)c2[tcol];
    unsigned long long m = 0ULL;
#pragma unroll
    for (int mf = 0; mf < 4; ++mf)
#pragma unroll
      for (int r = 0; r < 4; ++r) {
        unsigned node = (unsigned)(n0 + wy * 64 + mf * 16 + (l >> 4) * 4 + r);
        if (node == w1 || node == w2) continue;
        unsigned long long pk =
            ((unsigned long long)fkey(acc[mf][nf][r] * scl) << 32) | node;
        if (pk > m) m = pk;
      }
    if (m) atomicMax(&c3[tcol], m);
  }
  __syncthreads();
  if (tid < 128) {
    size_t base = ((size_t)b * TT + (t0 + tid)) * 8 + blockIdx.y;
    cand1[base] = c1[tid];
    cand2[base] = c2[tid];
    cand3[base] = c3[tid];
  }
}

__global__ __launch_bounds__(256) void fill_zero(unsigned* __restrict__ p, long long n) {
  long long i = (long long)blockIdx.x * 256 + threadIdx.x;
  long long stride = (long long)gridDim.x * 256;
  for (; i < n; i += stride) p[i] = 0u;
}

// ---------------------------------------------------------------------------
// Merge 8x(top-3) -> global top1 + rivals within GAP_MARGIN -> flag lists.
// ---------------------------------------------------------------------------
__global__ __launch_bounds__(256) void merge_flag_kernel(
    const unsigned long long* __restrict__ cand1,
    const unsigned long long* __restrict__ cand2,
    const unsigned long long* __restrict__ cand3,
    unsigned long long* __restrict__ amaxIdx,
    unsigned* __restrict__ counts, unsigned* __restrict__ flaglist,
    unsigned* __restrict__ clist) {
  int bt = blockIdx.x * 256 + threadIdx.x;  // [0, B*T)
  int b = bt >> 11;
  unsigned long long best = 0ULL;
#pragma unroll
  for (int nb = 0; nb < 8; ++nb) {
    unsigned long long v = cand1[(size_t)bt * 8 + nb];
    if (v > best) best = v;
  }
  amaxIdx[bt] = best;
  float v1 = fdec((unsigned)(best >> 32));
  float thr = v1 - GAP_MARGIN;
  unsigned bestnode = (unsigned)best;

  unsigned nodes[MAXC];
  int cnt = 0;
#pragma unroll
  for (int nb = 0; nb < 8; ++nb) {
    unsigned long long cs[3] = {cand1[(size_t)bt * 8 + nb], cand2[(size_t)bt * 8 + nb],
                                cand3[(size_t)bt * 8 + nb]};
#pragma unroll
    for (int s = 0; s < 3; ++s) {
      float v = fdec((unsigned)(cs[s] >> 32));
      unsigned nd = (unsigned)cs[s];
      if (v >= thr && nd != bestnode && cnt < MAXC) nodes[cnt++] = nd;
    }
  }
  if (cnt > 0) {
    unsigned p = atomicAdd(&counts[b], 1u);
    flaglist[b * TT + p] = (unsigned)bt;
    clist[(size_t)bt * 8] = (unsigned)(cnt + 1);
    clist[(size_t)bt * 8 + 1] = bestnode;
    for (int i = 0; i < cnt; ++i) clist[(size_t)bt * 8 + 2 + i] = nodes[i];
  }
}

// ---------------------------------------------------------------------------
// Exact f64 recheck, ONE FLAG PER BLOCK (grid-stride over flags).
//   k64[d] = x_t . Wk[d,:]  (f64, 2 rows/thread, 4-way ILP)
//   z[t']  = x[t',:] . k64  (f64 acc, f32 store; 8 t'/thread, 4-way ILP)
//   sim64(n) = Wq[n,:].z + bq[n]*sum(k64)  -- candidates only, wave-reduce.
// ---------------------------------------------------------------------------
__global__ __launch_bounds__(256) void recheck_kernel(
    const float* __restrict__ x, const float* __restrict__ Wq,
    const float* __restrict__ bq, const float* __restrict__ Wk,
    const unsigned* __restrict__ counts, const unsigned* __restrict__ flaglist,
    const unsigned* __restrict__ clist, unsigned long long* __restrict__ amaxIdx) {
  __shared__ float xs[CC];      // 2 KB
  __shared__ double k64[CC];    // 4 KB
  __shared__ float zs[TT];      // 8 KB
  __shared__ double red[4];
  __shared__ double ssumS;

  const int b = blockIdx.y;
  const unsigned cnt = counts[b];
  const int tid = threadIdx.x;
  const float* xb = x + (size_t)b * TT * CC;

  for (unsigned fi = blockIdx.x; fi < cnt; fi += gridDim.x) {
    unsigned bt = flaglist[b * TT + fi];
    int t = bt & (TT - 1);
    for (int c = tid; c < CC; c += 256) xs[c] = xb[(size_t)t * CC + c];
    __syncthreads();

    // k64 rows, 2 per thread, 4 accumulators each
    for (int d = tid; d < CC; d += 256) {
      const float* wr = Wk + (size_t)d * CC;
      double a0 = 0, a1 = 0, a2 = 0, a3 = 0;
      for (int c = 0; c < CC; c += 4) {
        a0 = fma((double)xs[c], (double)wr[c], a0);
        a1 = fma((double)xs[c + 1], (double)wr[c + 1], a1);
        a2 = fma((double)xs[c + 2], (double)wr[c + 2], a2);
        a3 = fma((double)xs[c + 3], (double)wr[c + 3], a3);
      }
      k64[d] = (a0 + a1) + (a2 + a3);
    }
    __syncthreads();

    if (tid == 0) {
      double s = 0.0;
      for (int c = 0; c < CC; ++c) s += k64[c];
      ssumS = s;
    }
    // z[t'] = x[t',:] . k64 ; 8 tokens per thread, 4 accumulators
    for (int i = 0; i < TT / 256; ++i) {
      int tp = tid + i * 256;
      const float* xr = xb + (size_t)tp * CC;
      double a0 = 0, a1 = 0, a2 = 0, a3 = 0;
      for (int c = 0; c < CC; c += 4) {
        a0 = fma((double)xr[c], k64[c], a0);
        a1 = fma((double)xr[c + 1], k64[c + 1], a1);
        a2 = fma((double)xr[c + 2], k64[c + 2], a2);
        a3 = fma((double)xr[c + 3], k64[c + 3], a3);
      }
      zs[tp] = (float)((a0 + a1) + (a2 + a3));
    }
    __syncthreads();

    const double scl = 0.04419417382415922;
    unsigned nc = clist[(size_t)bt * 8];
    unsigned long long bestpk = 0ULL;
    double bestv = -1e300;
    for (unsigned ci = 0; ci < nc; ++ci) {
      unsigned n = clist[(size_t)bt * 8 + 1 + ci];
      const float* wq = Wq + (size_t)n * TT;
      double a = 0.0;
#pragma unroll
      for (int i = 0; i < TT / 256; ++i) {
        int tp = tid + i * 256;
        a = fma((double)wq[tp], (double)zs[tp], a);
      }
#pragma unroll
      for (int off = 32; off > 0; off >>= 1) a += __shfl_down(a, off, 64);
      if ((tid & 63) == 0) red[tid >> 6] = a;
      __syncthreads();
      double s = (red[0] + red[1] + red[2] + red[3]) + (double)bq[n] * ssumS;
      if (s > bestv) {
        bestv = s;
        bestpk = ((unsigned long long)fkey((float)(s * scl)) << 32) | n;
      }
      __syncthreads();
    }
    if (tid == 0) amaxIdx[bt] = bestpk;
    __syncthreads();
  }
}

__global__ __launch_bounds__(256) void node_max_kernel(
    const unsigned long long* __restrict__ amaxIdx, unsigned* __restrict__ Mpack) {
  int i = blockIdx.x * 256 + threadIdx.x;
  unsigned long long pk = amaxIdx[i];
  int b = i >> 11;
  unsigned w = (unsigned)pk;
  atomicMax(&Mpack[b * NNODE + w], (unsigned)(pk >> 32));
}

__global__ __launch_bounds__(256) void node_denom_kernel(
    const unsigned long long* __restrict__ amaxIdx, const unsigned* __restrict__ Mpack,
    float* __restrict__ D, float* __restrict__ att_val) {
  int i = blockIdx.x * 256 + threadIdx.x;
  unsigned long long pk = amaxIdx[i];
  int b = i >> 11;
  unsigned w = (unsigned)pk;
  float amaxf = fdec((unsigned)(pk >> 32));
  float Mf = fdec(Mpack[b * NNODE + w]);
  float e = expf(amaxf - Mf);
  att_val[i] = e;
  atomicAdd(&D[b * NNODE + w], e);
}

__global__ __launch_bounds__(256) void att_write_kernel(
    const unsigned long long* __restrict__ amaxIdx, const float* __restrict__ D,
    float* __restrict__ att_val, float* __restrict__ att_out) {
  int i = blockIdx.x * 256 + threadIdx.x;
  unsigned long long pk = amaxIdx[i];
  int b = i >> 11;
  int t = i & (TT - 1);
  unsigned w = (unsigned)pk;
  float a = att_val[i] / D[b * NNODE + w];
  att_val[i] = a;
  att_out[((size_t)b * NNODE + w) * TT + t] = a;
}

__global__ __launch_bounds__(256) void pv_scatter_kernel(
    const unsigned long long* __restrict__ amaxIdx, const float* __restrict__ att_val,
    const unsigned short* __restrict__ v, float* __restrict__ out0) {
  int bt = blockIdx.x;  // [0, B*T)
  int b = bt >> 11;
  float a = att_val[bt];
  unsigned w = (unsigned)amaxIdx[bt];
  const unsigned short* vr = v + (size_t)bt * CC;
  float* orow = out0 + ((size_t)b * NNODE + w) * CC;
  for (int c = threadIdx.x; c < CC; c += 256)
    atomicAdd(&orow[c], a * bf16_tof(vr[c]));
}

extern "C" void kernel_launch(void* const* d_in, const int* in_sizes, int n_in,
                              void* d_out, int out_size, void* d_ws, size_t ws_size,
                              hipStream_t stream) {
  const float* x = (const float*)d_in[0];     // [B,T,C]  f32
  const float* Wq = (const float*)d_in[1];    // [N,T]
  const float* bq = (const float*)d_in[2];    // [N]
  const float* Wk = (const float*)d_in[3];    // [C,C]
  const float* Wv = (const float*)d_in[4];    // [C,C]
  const float* Wout = (const float*)d_in[5];  // [C,C]
  const float* bout = (const float*)d_in[6];  // [C]

  float* out = (float*)d_out;                      // [B,N,C] f32
  float* att_out = out + (size_t)BB * NNODE * CC;  // [B,N,T] f32

  // Workspace layout (f32 word units), ~71 MB total.
  float* ws = (float*)d_ws;
  float* q = ws;                                // B*N*C f32 (reused as out0)
  float* kbuf = q + (size_t)BB * NNODE * CC;    // B*T*C f32
  unsigned short* vbuf = (unsigned short*)(kbuf + (size_t)BB * TT * CC);  // bf16 bits
  unsigned long long* cand1 =
      (unsigned long long*)((unsigned*)vbuf + (size_t)BB * TT * CC / 2);  // B*T*8 u64
  unsigned long long* cand2 = cand1 + (size_t)BB * TT * 8;
  unsigned long long* cand3 = cand2 + (size_t)BB * TT * 8;
  unsigned long long* amaxIdx = cand3 + (size_t)BB * TT * 8;              // B*T u64
  unsigned* Mpack = (unsigned*)(amaxIdx + (size_t)BB * TT);               // B*N u32
  float* D = (float*)(Mpack + (size_t)BB * NNODE);                        // B*N f32
  unsigned* counts = (unsigned*)(D + (size_t)BB * NNODE);                 // 16 u32
  float* att_val = (float*)(counts + 16);                                 // B*T f32
  unsigned* flaglist = (unsigned*)(att_val + (size_t)BB * TT);            // B*T u32
  unsigned* clist = flaglist + (size_t)BB * TT;                           // B*T*8 u32
  float* out0 = q;

  dim3 blk(256);

  // Z1: zero Mpack | D | counts (contiguous)
  fill_zero<<<dim3(64), blk, 0, stream>>>(Mpack, (long long)BB * NNODE * 2 + 16);
  // Z2: zero att region of d_out
  fill_zero<<<dim3(4096), blk, 0, stream>>>((unsigned*)att_out,
                                            (long long)BB * NNODE * TT);

  // q[b,n,c] = sum_t Wq[n,t] x[b,t,c] + bq[n]  (bf16-split MFMA)
  mfma_gemm<true, false, 1><<<dim3(CC / 128, NNODE / 128, BB), blk, 0, stream>>>(
      Wq, x, q, bq, TT, TT, CC, CC, 0LL, (long long)TT * CC,
      (long long)NNODE * CC, 1.0f);

  // fused k (split, f32) + v (plain, bf16)
  mfma_kv<<<dim3(CC / 128, TT / 128, BB), blk, 0, stream>>>(x, Wk, Wv, kbuf, vbuf);

  // sim (split MFMA) + per-block top-3 candidates
  mfma_sim_top3<<<dim3(TT / 128, NNODE / 128, BB), blk, 0, stream>>>(
      q, kbuf, cand1, cand2, cand3);

  // merge -> amaxIdx + flagged-token candidate lists
  merge_flag_kernel<<<dim3(BB * TT / 256), blk, 0, stream>>>(
      cand1, cand2, cand3, amaxIdx, counts, flaglist, clist);

  // exact f64 recheck: one flag per block, 128 blocks per batch
  recheck_kernel<<<dim3(128, BB), blk, 0, stream>>>(
      x, Wq, bq, Wk, counts, flaglist, clist, amaxIdx);

  // zero out0 (aliases q; q dead after sim)
  fill_zero<<<dim3(2048), blk, 0, stream>>>((unsigned*)out0, (long long)BB * NNODE * CC);

  node_max_kernel<<<dim3(BB * TT / 256), blk, 0, stream>>>(amaxIdx, Mpack);
  node_denom_kernel<<<dim3(BB * TT / 256), blk, 0, stream>>>(amaxIdx, Mpack, D, att_val);
  att_write_kernel<<<dim3(BB * TT / 256), blk, 0, stream>>>(amaxIdx, D, att_val, att_out);

  // sparse PV scatter: out0[b,w,c] += att * v[b,t,c]
  pv_scatter_kernel<<<dim3(BB * TT), blk, 0, stream>>>(amaxIdx, att_val, vbuf, out0);

  // out[b,n,d] = sum_c out0[b,n,c] Wout[d,c] + bout[d]  (plain MFMA, flattened M)
  mfma_gemm<false, true, 2><<<dim3(CC / 128, BB * NNODE / 128, 1), blk, 0, stream>>>(
      out0, Wout, out, bout, CC, CC, CC, CC, 0LL, 0LL, 0LL, 1.0f);
}

// Round 10
// 781.224 us; speedup vs baseline: 1.3059x; 1.3059x over previous
//
#include <hip/hip_runtime.h>
#include <hip/hip_bf16.h>
#include <cfloat>

// Problem constants
#define BB 8
#define TT 2048
#define CC 512
#define NNODE 1024

#define GAP_MARGIN 1e-3f  // screening margin (~500x bf16-split-chain decision noise)
#define MAXC 6            // max rival candidates per flagged token (fits 8-slot clist)

typedef float f32x4 __attribute__((ext_vector_type(4)));
typedef short bf16x8 __attribute__((ext_vector_type(8)));
typedef float float4v __attribute__((ext_vector_type(4)));

// ---------------------------------------------------------------------------
// Order-preserving f32 <-> u32 key
// ---------------------------------------------------------------------------
__device__ __forceinline__ unsigned fkey(float v) {
  unsigned u = __float_as_uint(v);
  return (u & 0x80000000u) ? ~u : (u | 0x80000000u);
}
__device__ __forceinline__ float fdec(unsigned k) {
  unsigned u = (k & 0x80000000u) ? (k & 0x7FFFFFFFu) : ~k;
  return __uint_as_float(u);
}

// bf16 round-to-nearest-even helpers (bit-level)
__device__ __forceinline__ unsigned short bf16_rn(float f) {
  unsigned u = __float_as_uint(f);
  u += 0x7FFFu + ((u >> 16) & 1u);
  return (unsigned short)(u >> 16);
}
__device__ __forceinline__ float bf16_tof(unsigned short h) {
  return __uint_as_float(((unsigned)h) << 16);
}

// ---------------------------------------------------------------------------
// MFMA GEMM: C[m,n] = alpha*sum_k A[m,k]*B(k,n) (+bias), f32 in/out.
//   SPLIT: bf16-split (hh+hl+lh); TRANS_B: B is [N][K] row-major.
// 128x128 tile, BK=32, 256 threads (4 waves, 2x2), 16x16x32 frags.
// ---------------------------------------------------------------------------
template <bool SPLIT, bool TRANS_B, int BIAS_MODE>
__global__ __launch_bounds__(256) void mfma_gemm(
    const float* __restrict__ A, const float* __restrict__ Bm,
    float* __restrict__ Cp, const float* __restrict__ bias,
    int K, int lda, int ldb, int ldc,
    long long sA, long long sB, long long sC, float alpha) {
  __shared__ unsigned short Ah[128][40], Al[128][40], Bh[128][40], Bl[128][40];

  const int b = blockIdx.z;
  A += (long long)b * sA;
  Bm += (long long)b * sB;
  const int m0 = blockIdx.y * 128;
  const int n0 = blockIdx.x * 128;
  const int tid = threadIdx.x;
  const int l = tid & 63;
  const int wid = tid >> 6;
  const int wy = wid >> 1, wx = wid & 1;
  const int lrow = l & 15, lkb = (l >> 4) * 8;

  f32x4 acc[4][4] = {};

  for (int k0 = 0; k0 < K; k0 += 32) {
    {
      int r = tid >> 3, c = (tid & 7) * 4;
#pragma unroll
      for (int p = 0; p < 4; ++p, r += 32) {
        float4v v = *(const float4v*)(A + (long long)(m0 + r) * lda + k0 + c);
#pragma unroll
        for (int i = 0; i < 4; ++i) {
          unsigned short h = bf16_rn(v[i]);
          Ah[r][c + i] = h;
          if (SPLIT) Al[r][c + i] = bf16_rn(v[i] - bf16_tof(h));
        }
      }
    }
    if (TRANS_B) {
      int r = tid >> 3, c = (tid & 7) * 4;
#pragma unroll
      for (int p = 0; p < 4; ++p, r += 32) {
        float4v v = *(const float4v*)(Bm + (long long)(n0 + r) * ldb + k0 + c);
#pragma unroll
        for (int i = 0; i < 4; ++i) {
          unsigned short h = bf16_rn(v[i]);
          Bh[r][c + i] = h;
          if (SPLIT) Bl[r][c + i] = bf16_rn(v[i] - bf16_tof(h));
        }
      }
    } else {
      int kk = tid >> 5, c = (tid & 31) * 4;
#pragma unroll
      for (int p = 0; p < 4; ++p, kk += 8) {
        float4v v = *(const float4v*)(Bm + (long long)(k0 + kk) * ldb + n0 + c);
#pragma unroll
        for (int i = 0; i < 4; ++i) {
          unsigned short h = bf16_rn(v[i]);
          Bh[c + i][kk] = h;
          if (SPLIT) Bl[c + i][kk] = bf16_rn(v[i] - bf16_tof(h));
        }
      }
    }
    __syncthreads();

    bf16x8 ah[4], bh[4], al[4], bl[4];
#pragma unroll
    for (int mf = 0; mf < 4; ++mf) {
      ah[mf] = *(const bf16x8*)&Ah[wy * 64 + mf * 16 + lrow][lkb];
      if (SPLIT) al[mf] = *(const bf16x8*)&Al[wy * 64 + mf * 16 + lrow][lkb];
    }
#pragma unroll
    for (int nf = 0; nf < 4; ++nf) {
      bh[nf] = *(const bf16x8*)&Bh[wx * 64 + nf * 16 + lrow][lkb];
      if (SPLIT) bl[nf] = *(const bf16x8*)&Bl[wx * 64 + nf * 16 + lrow][lkb];
    }
#pragma unroll
    for (int mf = 0; mf < 4; ++mf)
#pragma unroll
      for (int nf = 0; nf < 4; ++nf) {
        acc[mf][nf] =
            __builtin_amdgcn_mfma_f32_16x16x32_bf16(ah[mf], bh[nf], acc[mf][nf], 0, 0, 0);
        if (SPLIT) {
          acc[mf][nf] =
              __builtin_amdgcn_mfma_f32_16x16x32_bf16(ah[mf], bl[nf], acc[mf][nf], 0, 0, 0);
          acc[mf][nf] =
              __builtin_amdgcn_mfma_f32_16x16x32_bf16(al[mf], bh[nf], acc[mf][nf], 0, 0, 0);
        }
      }
    __syncthreads();
  }

#pragma unroll
  for (int mf = 0; mf < 4; ++mf)
#pragma unroll
    for (int r = 0; r < 4; ++r) {
      int m = m0 + wy * 64 + mf * 16 + (l >> 4) * 4 + r;
#pragma unroll
      for (int nf = 0; nf < 4; ++nf) {
        int n = n0 + wx * 64 + nf * 16 + lrow;
        float v = acc[mf][nf][r] * alpha;
        if (BIAS_MODE == 1) v += bias[m];
        if (BIAS_MODE == 2) v += bias[n];
        Cp[sC * b + (long long)m * ldc + n] = v;
      }
    }
}

// ---------------------------------------------------------------------------
// Fused k (bf16-split, f32 out) + v (plain bf16, bf16 out) projection.
// ---------------------------------------------------------------------------
__global__ __launch_bounds__(256) void mfma_kv(
    const float* __restrict__ x, const float* __restrict__ Wk,
    const float* __restrict__ Wv, float* __restrict__ kout,
    unsigned short* __restrict__ vout) {
  __shared__ unsigned short Ah[128][40], Al[128][40], Bkh[128][40], Bkl[128][40],
      Bvh[128][40];

  const int b = blockIdx.z;
  const float* A = x + (size_t)b * TT * CC;
  const int m0 = blockIdx.y * 128;  // tokens
  const int n0 = blockIdx.x * 128;  // out dim
  const int tid = threadIdx.x;
  const int l = tid & 63;
  const int wid = tid >> 6;
  const int wy = wid >> 1, wx = wid & 1;
  const int lrow = l & 15, lkb = (l >> 4) * 8;

  f32x4 acck[4][4] = {}, accv[4][4] = {};

  for (int k0 = 0; k0 < CC; k0 += 32) {
    {
      int r = tid >> 3, c = (tid & 7) * 4;
#pragma unroll
      for (int p = 0; p < 4; ++p, r += 32) {
        float4v v = *(const float4v*)(A + (size_t)(m0 + r) * CC + k0 + c);
        float4v wk = *(const float4v*)(Wk + (size_t)(n0 + r) * CC + k0 + c);
        float4v wv = *(const float4v*)(Wv + (size_t)(n0 + r) * CC + k0 + c);
#pragma unroll
        for (int i = 0; i < 4; ++i) {
          unsigned short h = bf16_rn(v[i]);
          Ah[r][c + i] = h;
          Al[r][c + i] = bf16_rn(v[i] - bf16_tof(h));
          unsigned short hk = bf16_rn(wk[i]);
          Bkh[r][c + i] = hk;
          Bkl[r][c + i] = bf16_rn(wk[i] - bf16_tof(hk));
          Bvh[r][c + i] = bf16_rn(wv[i]);
        }
      }
    }
    __syncthreads();

    bf16x8 ah[4], al[4], bkh[4], bkl[4], bvh[4];
#pragma unroll
    for (int mf = 0; mf < 4; ++mf) {
      ah[mf] = *(const bf16x8*)&Ah[wy * 64 + mf * 16 + lrow][lkb];
      al[mf] = *(const bf16x8*)&Al[wy * 64 + mf * 16 + lrow][lkb];
    }
#pragma unroll
    for (int nf = 0; nf < 4; ++nf) {
      bkh[nf] = *(const bf16x8*)&Bkh[wx * 64 + nf * 16 + lrow][lkb];
      bkl[nf] = *(const bf16x8*)&Bkl[wx * 64 + nf * 16 + lrow][lkb];
      bvh[nf] = *(const bf16x8*)&Bvh[wx * 64 + nf * 16 + lrow][lkb];
    }
#pragma unroll
    for (int mf = 0; mf < 4; ++mf)
#pragma unroll
      for (int nf = 0; nf < 4; ++nf) {
        acck[mf][nf] =
            __builtin_amdgcn_mfma_f32_16x16x32_bf16(ah[mf], bkh[nf], acck[mf][nf], 0, 0, 0);
        acck[mf][nf] =
            __builtin_amdgcn_mfma_f32_16x16x32_bf16(ah[mf], bkl[nf], acck[mf][nf], 0, 0, 0);
        acck[mf][nf] =
            __builtin_amdgcn_mfma_f32_16x16x32_bf16(al[mf], bkh[nf], acck[mf][nf], 0, 0, 0);
        accv[mf][nf] =
            __builtin_amdgcn_mfma_f32_16x16x32_bf16(ah[mf], bvh[nf], accv[mf][nf], 0, 0, 0);
      }
    __syncthreads();
  }

#pragma unroll
  for (int mf = 0; mf < 4; ++mf)
#pragma unroll
    for (int r = 0; r < 4; ++r) {
      int m = m0 + wy * 64 + mf * 16 + (l >> 4) * 4 + r;
#pragma unroll
      for (int nf = 0; nf < 4; ++nf) {
        int n = n0 + wx * 64 + nf * 16 + lrow;
        size_t off = ((size_t)b * TT + m) * CC + n;
        kout[off] = acck[mf][nf][r];
        vout[off] = bf16_rn(accv[mf][nf][r]);
      }
    }
}

// ---------------------------------------------------------------------------
// sim (bf16-split MFMA, no store) + per-block per-token top-3 candidates.
// ---------------------------------------------------------------------------
__global__ __launch_bounds__(256) void mfma_sim_top3(
    const float* __restrict__ q, const float* __restrict__ kb,
    unsigned long long* __restrict__ cand1, unsigned long long* __restrict__ cand2,
    unsigned long long* __restrict__ cand3) {
  __shared__ unsigned short Ah[128][40], Al[128][40], Bh[128][40], Bl[128][40];
  __shared__ unsigned long long c1[128], c2[128], c3[128];

  const int b = blockIdx.z;
  const float* A = q + (size_t)b * NNODE * CC;
  const float* Bm = kb + (size_t)b * TT * CC;
  const int n0 = blockIdx.y * 128;  // nodes
  const int t0 = blockIdx.x * 128;  // tokens
  const int tid = threadIdx.x;
  const int l = tid & 63;
  const int wid = tid >> 6;
  const int wy = wid >> 1, wx = wid & 1;
  const int lrow = l & 15, lkb = (l >> 4) * 8;

  if (tid < 128) { c1[tid] = 0ULL; c2[tid] = 0ULL; c3[tid] = 0ULL; }

  f32x4 acc[4][4] = {};

  for (int k0 = 0; k0 < CC; k0 += 32) {
    {
      int r = tid >> 3, c = (tid & 7) * 4;
#pragma unroll
      for (int p = 0; p < 4; ++p, r += 32) {
        float4v v = *(const float4v*)(A + (size_t)(n0 + r) * CC + k0 + c);
        float4v w = *(const float4v*)(Bm + (size_t)(t0 + r) * CC + k0 + c);
#pragma unroll
        for (int i = 0; i < 4; ++i) {
          unsigned short h = bf16_rn(v[i]);
          Ah[r][c + i] = h;
          Al[r][c + i] = bf16_rn(v[i] - bf16_tof(h));
          unsigned short hb = bf16_rn(w[i]);
          Bh[r][c + i] = hb;
          Bl[r][c + i] = bf16_rn(w[i] - bf16_tof(hb));
        }
      }
    }
    __syncthreads();

    bf16x8 ah[4], al[4], bh[4], bl[4];
#pragma unroll
    for (int mf = 0; mf < 4; ++mf) {
      ah[mf] = *(const bf16x8*)&Ah[wy * 64 + mf * 16 + lrow][lkb];
      al[mf] = *(const bf16x8*)&Al[wy * 64 + mf * 16 + lrow][lkb];
    }
#pragma unroll
    for (int nf = 0; nf < 4; ++nf) {
      bh[nf] = *(const bf16x8*)&Bh[wx * 64 + nf * 16 + lrow][lkb];
      bl[nf] = *(const bf16x8*)&Bl[wx * 64 + nf * 16 + lrow][lkb];
    }
#pragma unroll
    for (int mf = 0; mf < 4; ++mf)
#pragma unroll
      for (int nf = 0; nf < 4; ++nf) {
        acc[mf][nf] =
            __builtin_amdgcn_mfma_f32_16x16x32_bf16(ah[mf], bh[nf], acc[mf][nf], 0, 0, 0);
        acc[mf][nf] =
            __builtin_amdgcn_mfma_f32_16x16x32_bf16(ah[mf], bl[nf], acc[mf][nf], 0, 0, 0);
        acc[mf][nf] =
            __builtin_amdgcn_mfma_f32_16x16x32_bf16(al[mf], bh[nf], acc[mf][nf], 0, 0, 0);
      }
    __syncthreads();
  }

  const float scl = 0.04419417382415922f;
#pragma unroll
  for (int nf = 0; nf < 4; ++nf) {
    int tcol = wx * 64 + nf * 16 + lrow;
    unsigned long long m = 0ULL;
#pragma unroll
    for (int mf = 0; mf < 4; ++mf)
#pragma unroll
      for (int r = 0; r < 4; ++r) {
        unsigned node = (unsigned)(n0 + wy * 64 + mf * 16 + (l >> 4) * 4 + r);
        unsigned long long pk =
            ((unsigned long long)fkey(acc[mf][nf][r] * scl) << 32) | node;
        if (pk > m) m = pk;
      }
    atomicMax(&c1[tcol], m);
  }
  __syncthreads();
#pragma unroll
  for (int nf = 0; nf < 4; ++nf) {
    int tcol = wx * 64 + nf * 16 + lrow;
    unsigned w1 = (unsigned)c1[tcol];
    unsigned long long m = 0ULL;
#pragma unroll
    for (int mf = 0; mf < 4; ++mf)
#pragma unroll
      for (int r = 0; r < 4; ++r) {
        unsigned node = (unsigned)(n0 + wy * 64 + mf * 16 + (l >> 4) * 4 + r);
        if (node == w1) continue;
        unsigned long long pk =
            ((unsigned long long)fkey(acc[mf][nf][r] * scl) << 32) | node;
        if (pk > m) m = pk;
      }
    if (m) atomicMax(&c2[tcol], m);
  }
  __syncthreads();
#pragma unroll
  for (int nf = 0; nf < 4; ++nf) {
    int tcol = wx * 64 + nf * 16 + lrow;
    unsigned w1 = (unsigned)c1[tcol];
    unsigned w2 = (unsigned)c2[tcol];
    unsigned long long m = 0ULL;
#pragma unroll
    for (int mf = 0; mf < 4; ++mf)
#pragma unroll
      for (int r = 0; r < 4; ++r) {
        unsigned node = (unsigned)(n0 + wy * 64 + mf * 16 + (l >> 4) * 4 + r);
        if (node == w1 || node == w2) continue;
        unsigned long long pk =
            ((unsigned long long)fkey(acc[mf][nf][r] * scl) << 32) | node;
        if (pk > m) m = pk;
      }
    if (m) atomicMax(&c3[tcol], m);
  }
  __syncthreads();
  if (tid < 128) {
    size_t base = ((size_t)b * TT + (t0 + tid)) * 8 + blockIdx.y;
    cand1[base] = c1[tid];
    cand2[base] = c2[tid];
    cand3[base] = c3[tid];
  }
}

__global__ __launch_bounds__(256) void fill_zero(unsigned* __restrict__ p, long long n) {
  long long i = (long long)blockIdx.x * 256 + threadIdx.x;
  long long stride = (long long)gridDim.x * 256;
  for (; i < n; i += stride) p[i] = 0u;
}

// ---------------------------------------------------------------------------
// Merge 8x(top-3) -> global top1 + rivals within GAP_MARGIN -> flag lists.
// ---------------------------------------------------------------------------
__global__ __launch_bounds__(256) void merge_flag_kernel(
    const unsigned long long* __restrict__ cand1,
    const unsigned long long* __restrict__ cand2,
    const unsigned long long* __restrict__ cand3,
    unsigned long long* __restrict__ amaxIdx,
    unsigned* __restrict__ counts, unsigned* __restrict__ flaglist,
    unsigned* __restrict__ clist) {
  int bt = blockIdx.x * 256 + threadIdx.x;  // [0, B*T)
  int b = bt >> 11;
  unsigned long long best = 0ULL;
#pragma unroll
  for (int nb = 0; nb < 8; ++nb) {
    unsigned long long v = cand1[(size_t)bt * 8 + nb];
    if (v > best) best = v;
  }
  amaxIdx[bt] = best;
  float v1 = fdec((unsigned)(best >> 32));
  float thr = v1 - GAP_MARGIN;
  unsigned bestnode = (unsigned)best;

  unsigned nodes[MAXC];
  int cnt = 0;
#pragma unroll
  for (int nb = 0; nb < 8; ++nb) {
    unsigned long long cs[3] = {cand1[(size_t)bt * 8 + nb], cand2[(size_t)bt * 8 + nb],
                                cand3[(size_t)bt * 8 + nb]};
#pragma unroll
    for (int s = 0; s < 3; ++s) {
      float v = fdec((unsigned)(cs[s] >> 32));
      unsigned nd = (unsigned)cs[s];
      if (v >= thr && nd != bestnode && cnt < MAXC) nodes[cnt++] = nd;
    }
  }
  if (cnt > 0) {
    unsigned p = atomicAdd(&counts[b], 1u);
    flaglist[b * TT + p] = (unsigned)bt;
    clist[(size_t)bt * 8] = (unsigned)(cnt + 1);
    clist[(size_t)bt * 8 + 1] = bestnode;
    for (int i = 0; i < cnt; ++i) clist[(size_t)bt * 8 + 2 + i] = nodes[i];
  }
}

// ---------------------------------------------------------------------------
// Exact f64 recheck, PARALLEL: grid (16 flag-slots x 8 token-chunks, B).
// Per chunk-block: stage x_t, full k64, z for 256 tokens (reg), per-candidate
// block-reduced partial Wq.z -> f64 atomicAdd into cacc[bt*8+ci].
// chunk 0 adds bq[n]*sum(k64). recheck_final argmaxes cacc.
// ---------------------------------------------------------------------------
__global__ __launch_bounds__(256) void recheck_partial(
    const float* __restrict__ x, const float* __restrict__ Wq,
    const float* __restrict__ bq, const float* __restrict__ Wk,
    const unsigned* __restrict__ counts, const unsigned* __restrict__ flaglist,
    const unsigned* __restrict__ clist, double* __restrict__ cacc) {
  __shared__ float xs[CC];
  __shared__ double k64[CC];
  __shared__ double red[4];

  const int b = blockIdx.y;
  const unsigned cnt = counts[b];
  const int tid = threadIdx.x;
  const int fslot = blockIdx.x >> 3;  // 16 slots
  const int chunk = blockIdx.x & 7;   // 8 chunks x 256 tokens
  const float* xb = x + (size_t)b * TT * CC;

  for (unsigned fi = fslot; fi < cnt; fi += 16) {
    unsigned bt = flaglist[b * TT + fi];
    int t = bt & (TT - 1);
    for (int c = tid; c < CC; c += 256) xs[c] = xb[(size_t)t * CC + c];
    __syncthreads();

    // k64 rows, 2 per thread, 4-way ILP
    for (int d = tid; d < CC; d += 256) {
      const float* wr = Wk + (size_t)d * CC;
      double a0 = 0, a1 = 0, a2 = 0, a3 = 0;
      for (int c = 0; c < CC; c += 4) {
        a0 = fma((double)xs[c], (double)wr[c], a0);
        a1 = fma((double)xs[c + 1], (double)wr[c + 1], a1);
        a2 = fma((double)xs[c + 2], (double)wr[c + 2], a2);
        a3 = fma((double)xs[c + 3], (double)wr[c + 3], a3);
      }
      k64[d] = (a0 + a1) + (a2 + a3);
    }
    __syncthreads();

    // ssum = sum(k64), block-reduce
    double ps = k64[tid] + k64[tid + 256];
#pragma unroll
    for (int off = 32; off > 0; off >>= 1) ps += __shfl_down(ps, off, 64);
    if ((tid & 63) == 0) red[tid >> 6] = ps;
    __syncthreads();
    double ssum = red[0] + red[1] + red[2] + red[3];
    __syncthreads();

    // z for my token (register)
    int tp = chunk * 256 + tid;
    const float* xr = xb + (size_t)tp * CC;
    double a0 = 0, a1 = 0, a2 = 0, a3 = 0;
    for (int c = 0; c < CC; c += 4) {
      a0 = fma((double)xr[c], k64[c], a0);
      a1 = fma((double)xr[c + 1], k64[c + 1], a1);
      a2 = fma((double)xr[c + 2], k64[c + 2], a2);
      a3 = fma((double)xr[c + 3], k64[c + 3], a3);
    }
    double z = (a0 + a1) + (a2 + a3);

    // per-candidate partial dot over this chunk
    unsigned ncand = clist[(size_t)bt * 8];
    for (unsigned ci = 0; ci < ncand; ++ci) {
      unsigned n = clist[(size_t)bt * 8 + 1 + ci];
      double term = (double)Wq[(size_t)n * TT + tp] * z;
#pragma unroll
      for (int off = 32; off > 0; off >>= 1) term += __shfl_down(term, off, 64);
      if ((tid & 63) == 0) red[tid >> 6] = term;
      __syncthreads();
      if (tid == 0) {
        double s = red[0] + red[1] + red[2] + red[3];
        if (chunk == 0) s += (double)bq[n] * ssum;
        atomicAdd(&cacc[(size_t)bt * 8 + ci], s);
      }
      __syncthreads();
    }
    __syncthreads();
  }
}

__global__ __launch_bounds__(256) void recheck_final(
    const unsigned* __restrict__ clist, const double* __restrict__ cacc,
    unsigned long long* __restrict__ amaxIdx) {
  int bt = blockIdx.x * 256 + threadIdx.x;  // [0, B*T)
  unsigned ncand = clist[(size_t)bt * 8];
  if (ncand == 0) return;
  const double scl = 0.04419417382415922;
  double bestv = -1e300;
  unsigned bestn = 0;
  for (unsigned ci = 0; ci < ncand; ++ci) {
    double s = cacc[(size_t)bt * 8 + ci];
    if (s > bestv) { bestv = s; bestn = clist[(size_t)bt * 8 + 1 + ci]; }
  }
  amaxIdx[bt] = ((unsigned long long)fkey((float)(bestv * scl)) << 32) | bestn;
}

__global__ __launch_bounds__(256) void node_max_kernel(
    const unsigned long long* __restrict__ amaxIdx, unsigned* __restrict__ Mpack) {
  int i = blockIdx.x * 256 + threadIdx.x;
  unsigned long long pk = amaxIdx[i];
  int b = i >> 11;
  unsigned w = (unsigned)pk;
  atomicMax(&Mpack[b * NNODE + w], (unsigned)(pk >> 32));
}

__global__ __launch_bounds__(256) void node_denom_kernel(
    const unsigned long long* __restrict__ amaxIdx, const unsigned* __restrict__ Mpack,
    float* __restrict__ D, float* __restrict__ att_val) {
  int i = blockIdx.x * 256 + threadIdx.x;
  unsigned long long pk = amaxIdx[i];
  int b = i >> 11;
  unsigned w = (unsigned)pk;
  float amaxf = fdec((unsigned)(pk >> 32));
  float Mf = fdec(Mpack[b * NNODE + w]);
  float e = expf(amaxf - Mf);
  att_val[i] = e;
  atomicAdd(&D[b * NNODE + w], e);
}

__global__ __launch_bounds__(256) void att_write_kernel(
    const unsigned long long* __restrict__ amaxIdx, const float* __restrict__ D,
    float* __restrict__ att_val, float* __restrict__ att_out) {
  int i = blockIdx.x * 256 + threadIdx.x;
  unsigned long long pk = amaxIdx[i];
  int b = i >> 11;
  int t = i & (TT - 1);
  unsigned w = (unsigned)pk;
  float a = att_val[i] / D[b * NNODE + w];
  att_val[i] = a;
  att_out[((size_t)b * NNODE + w) * TT + t] = a;
}

__global__ __launch_bounds__(256) void pv_scatter_kernel(
    const unsigned long long* __restrict__ amaxIdx, const float* __restrict__ att_val,
    const unsigned short* __restrict__ v, float* __restrict__ out0) {
  int bt = blockIdx.x;  // [0, B*T)
  int b = bt >> 11;
  float a = att_val[bt];
  unsigned w = (unsigned)amaxIdx[bt];
  const unsigned short* vr = v + (size_t)bt * CC;
  float* orow = out0 + ((size_t)b * NNODE + w) * CC;
  for (int c = threadIdx.x; c < CC; c += 256)
    atomicAdd(&orow[c], a * bf16_tof(vr[c]));
}

extern "C" void kernel_launch(void* const* d_in, const int* in_sizes, int n_in,
                              void* d_out, int out_size, void* d_ws, size_t ws_size,
                              hipStream_t stream) {
  const float* x = (const float*)d_in[0];     // [B,T,C]  f32
  const float* Wq = (const float*)d_in[1];    // [N,T]
  const float* bq = (const float*)d_in[2];    // [N]
  const float* Wk = (const float*)d_in[3];    // [C,C]
  const float* Wv = (const float*)d_in[4];    // [C,C]
  const float* Wout = (const float*)d_in[5];  // [C,C]
  const float* bout = (const float*)d_in[6];  // [C]

  float* out = (float*)d_out;                      // [B,N,C] f32
  float* att_out = out + (size_t)BB * NNODE * CC;  // [B,N,T] f32

  // Workspace layout (f32 word units), ~73 MB total.
  float* ws = (float*)d_ws;
  float* q = ws;                                // B*N*C f32 (reused as out0)
  float* kbuf = q + (size_t)BB * NNODE * CC;    // B*T*C f32
  unsigned short* vbuf = (unsigned short*)(kbuf + (size_t)BB * TT * CC);  // bf16 bits
  unsigned long long* cand1 =
      (unsigned long long*)((unsigned*)vbuf + (size_t)BB * TT * CC / 2);  // B*T*8 u64
  unsigned long long* cand2 = cand1 + (size_t)BB * TT * 8;
  unsigned long long* cand3 = cand2 + (size_t)BB * TT * 8;
  unsigned long long* amaxIdx = cand3 + (size_t)BB * TT * 8;              // B*T u64
  unsigned* Mpack = (unsigned*)(amaxIdx + (size_t)BB * TT);               // B*N u32
  float* D = (float*)(Mpack + (size_t)BB * NNODE);                        // B*N f32
  unsigned* counts = (unsigned*)(D + (size_t)BB * NNODE);                 // 16 u32
  float* att_val = (float*)(counts + 16);                                 // B*T f32
  unsigned* flaglist = (unsigned*)(att_val + (size_t)BB * TT);            // B*T u32
  unsigned* clist = flaglist + (size_t)BB * TT;                           // B*T*8 u32
  double* cacc = (double*)(clist + (size_t)BB * TT * 8);                  // B*T*8 f64
  float* out0 = q;

  dim3 blk(256);

  // Z1: zero Mpack | D | counts (contiguous)
  fill_zero<<<dim3(64), blk, 0, stream>>>(Mpack, (long long)BB * NNODE * 2 + 16);
  // Z1b: zero clist + cacc (contiguous; 1.5 MB)
  fill_zero<<<dim3(384), blk, 0, stream>>>(
      clist, (long long)BB * TT * 8 + (long long)BB * TT * 16);
  // Z2: zero att region of d_out
  fill_zero<<<dim3(4096), blk, 0, stream>>>((unsigned*)att_out,
                                            (long long)BB * NNODE * TT);

  // q[b,n,c] = sum_t Wq[n,t] x[b,t,c] + bq[n]  (bf16-split MFMA)
  mfma_gemm<true, false, 1><<<dim3(CC / 128, NNODE / 128, BB), blk, 0, stream>>>(
      Wq, x, q, bq, TT, TT, CC, CC, 0LL, (long long)TT * CC,
      (long long)NNODE * CC, 1.0f);

  // fused k (split, f32) + v (plain, bf16)
  mfma_kv<<<dim3(CC / 128, TT / 128, BB), blk, 0, stream>>>(x, Wk, Wv, kbuf, vbuf);

  // sim (split MFMA) + per-block top-3 candidates
  mfma_sim_top3<<<dim3(TT / 128, NNODE / 128, BB), blk, 0, stream>>>(
      q, kbuf, cand1, cand2, cand3);

  // merge -> amaxIdx + flagged-token candidate lists
  merge_flag_kernel<<<dim3(BB * TT / 256), blk, 0, stream>>>(
      cand1, cand2, cand3, amaxIdx, counts, flaglist, clist);

  // exact f64 recheck: parallel partial sums + finalize
  recheck_partial<<<dim3(128, BB), blk, 0, stream>>>(
      x, Wq, bq, Wk, counts, flaglist, clist, cacc);
  recheck_final<<<dim3(BB * TT / 256), blk, 0, stream>>>(clist, cacc, amaxIdx);

  // zero out0 (aliases q; q dead after sim)
  fill_zero<<<dim3(2048), blk, 0, stream>>>((unsigned*)out0, (long long)BB * NNODE * CC);

  node_max_kernel<<<dim3(BB * TT / 256), blk, 0, stream>>>(amaxIdx, Mpack);
  node_denom_kernel<<<dim3(BB * TT / 256), blk, 0, stream>>>(amaxIdx, Mpack, D, att_val);
  att_write_kernel<<<dim3(BB * TT / 256), blk, 0, stream>>>(amaxIdx, D, att_val, att_out);

  // sparse PV scatter: out0[b,w,c] += att * v[b,t,c]
  pv_scatter_kernel<<<dim3(BB * TT), blk, 0, stream>>>(amaxIdx, att_val, vbuf, out0);

  // out[b,n,d] = sum_c out0[b,n,c] Wout[d,c] + bout[d]  (plain MFMA, flattened M)
  mfma_gemm<false, true, 2><<<dim3(CC / 128, BB * NNODE / 128, 1), blk, 0, stream>>>(
      out0, Wout, out, bout, CC, CC, CC, CC, 0LL, 0LL, 0LL, 1.0f);
}

// Round 11
// 716.426 us; speedup vs baseline: 1.4241x; 1.0904x over previous
//
#include <hip/hip_runtime.h>
#include <hip/hip_bf16.h>
#include <cfloat>

// Problem constants
#define BB 8
#define TT 2048
#define CC 512
#define NNODE 1024

#define GAP_MARGIN 2e-4f  // screening margin (~20 sigma of bf16-split screen noise)
#define MAXC 6            // max rival candidates per flagged token (fits 8-slot clist)

typedef float f32x4 __attribute__((ext_vector_type(4)));
typedef short bf16x8 __attribute__((ext_vector_type(8)));
typedef float float4v __attribute__((ext_vector_type(4)));

// ---------------------------------------------------------------------------
// Order-preserving f32 <-> u32 key
// ---------------------------------------------------------------------------
__device__ __forceinline__ unsigned fkey(float v) {
  unsigned u = __float_as_uint(v);
  return (u & 0x80000000u) ? ~u : (u | 0x80000000u);
}
__device__ __forceinline__ float fdec(unsigned k) {
  unsigned u = (k & 0x80000000u) ? (k & 0x7FFFFFFFu) : ~k;
  return __uint_as_float(u);
}

// bf16 round-to-nearest-even helpers (bit-level)
__device__ __forceinline__ unsigned short bf16_rn(float f) {
  unsigned u = __float_as_uint(f);
  u += 0x7FFFu + ((u >> 16) & 1u);
  return (unsigned short)(u >> 16);
}
__device__ __forceinline__ float bf16_tof(unsigned short h) {
  return __uint_as_float(((unsigned)h) << 16);
}

// ---------------------------------------------------------------------------
// MFMA GEMM: C[m,n] = alpha*sum_k A[m,k]*B(k,n) (+bias), f32 in/out.
//   SPLIT: bf16-split (hh+hl+lh); TRANS_B: B is [N][K] row-major.
// 128x128 tile, BK=32, 256 threads (4 waves, 2x2), 16x16x32 frags.
// ---------------------------------------------------------------------------
template <bool SPLIT, bool TRANS_B, int BIAS_MODE>
__global__ __launch_bounds__(256) void mfma_gemm(
    const float* __restrict__ A, const float* __restrict__ Bm,
    float* __restrict__ Cp, const float* __restrict__ bias,
    int K, int lda, int ldb, int ldc,
    long long sA, long long sB, long long sC, float alpha) {
  __shared__ unsigned short Ah[128][40], Al[128][40], Bh[128][40], Bl[128][40];

  const int b = blockIdx.z;
  A += (long long)b * sA;
  Bm += (long long)b * sB;
  const int m0 = blockIdx.y * 128;
  const int n0 = blockIdx.x * 128;
  const int tid = threadIdx.x;
  const int l = tid & 63;
  const int wid = tid >> 6;
  const int wy = wid >> 1, wx = wid & 1;
  const int lrow = l & 15, lkb = (l >> 4) * 8;

  f32x4 acc[4][4] = {};

  for (int k0 = 0; k0 < K; k0 += 32) {
    {
      int r = tid >> 3, c = (tid & 7) * 4;
#pragma unroll
      for (int p = 0; p < 4; ++p, r += 32) {
        float4v v = *(const float4v*)(A + (long long)(m0 + r) * lda + k0 + c);
#pragma unroll
        for (int i = 0; i < 4; ++i) {
          unsigned short h = bf16_rn(v[i]);
          Ah[r][c + i] = h;
          if (SPLIT) Al[r][c + i] = bf16_rn(v[i] - bf16_tof(h));
        }
      }
    }
    if (TRANS_B) {
      int r = tid >> 3, c = (tid & 7) * 4;
#pragma unroll
      for (int p = 0; p < 4; ++p, r += 32) {
        float4v v = *(const float4v*)(Bm + (long long)(n0 + r) * ldb + k0 + c);
#pragma unroll
        for (int i = 0; i < 4; ++i) {
          unsigned short h = bf16_rn(v[i]);
          Bh[r][c + i] = h;
          if (SPLIT) Bl[r][c + i] = bf16_rn(v[i] - bf16_tof(h));
        }
      }
    } else {
      int kk = tid >> 5, c = (tid & 31) * 4;
#pragma unroll
      for (int p = 0; p < 4; ++p, kk += 8) {
        float4v v = *(const float4v*)(Bm + (long long)(k0 + kk) * ldb + n0 + c);
#pragma unroll
        for (int i = 0; i < 4; ++i) {
          unsigned short h = bf16_rn(v[i]);
          Bh[c + i][kk] = h;
          if (SPLIT) Bl[c + i][kk] = bf16_rn(v[i] - bf16_tof(h));
        }
      }
    }
    __syncthreads();

    bf16x8 ah[4], bh[4], al[4], bl[4];
#pragma unroll
    for (int mf = 0; mf < 4; ++mf) {
      ah[mf] = *(const bf16x8*)&Ah[wy * 64 + mf * 16 + lrow][lkb];
      if (SPLIT) al[mf] = *(const bf16x8*)&Al[wy * 64 + mf * 16 + lrow][lkb];
    }
#pragma unroll
    for (int nf = 0; nf < 4; ++nf) {
      bh[nf] = *(const bf16x8*)&Bh[wx * 64 + nf * 16 + lrow][lkb];
      if (SPLIT) bl[nf] = *(const bf16x8*)&Bl[wx * 64 + nf * 16 + lrow][lkb];
    }
#pragma unroll
    for (int mf = 0; mf < 4; ++mf)
#pragma unroll
      for (int nf = 0; nf < 4; ++nf) {
        acc[mf][nf] =
            __builtin_amdgcn_mfma_f32_16x16x32_bf16(ah[mf], bh[nf], acc[mf][nf], 0, 0, 0);
        if (SPLIT) {
          acc[mf][nf] =
              __builtin_amdgcn_mfma_f32_16x16x32_bf16(ah[mf], bl[nf], acc[mf][nf], 0, 0, 0);
          acc[mf][nf] =
              __builtin_amdgcn_mfma_f32_16x16x32_bf16(al[mf], bh[nf], acc[mf][nf], 0, 0, 0);
        }
      }
    __syncthreads();
  }

#pragma unroll
  for (int mf = 0; mf < 4; ++mf)
#pragma unroll
    for (int r = 0; r < 4; ++r) {
      int m = m0 + wy * 64 + mf * 16 + (l >> 4) * 4 + r;
#pragma unroll
      for (int nf = 0; nf < 4; ++nf) {
        int n = n0 + wx * 64 + nf * 16 + lrow;
        float v = acc[mf][nf][r] * alpha;
        if (BIAS_MODE == 1) v += bias[m];
        if (BIAS_MODE == 2) v += bias[n];
        Cp[sC * b + (long long)m * ldc + n] = v;
      }
    }
}

// ---------------------------------------------------------------------------
// Fused k (bf16-split, f32 out) + v (plain bf16, bf16 out) projection.
// ---------------------------------------------------------------------------
__global__ __launch_bounds__(256) void mfma_kv(
    const float* __restrict__ x, const float* __restrict__ Wk,
    const float* __restrict__ Wv, float* __restrict__ kout,
    unsigned short* __restrict__ vout) {
  __shared__ unsigned short Ah[128][40], Al[128][40], Bkh[128][40], Bkl[128][40],
      Bvh[128][40];

  const int b = blockIdx.z;
  const float* A = x + (size_t)b * TT * CC;
  const int m0 = blockIdx.y * 128;  // tokens
  const int n0 = blockIdx.x * 128;  // out dim
  const int tid = threadIdx.x;
  const int l = tid & 63;
  const int wid = tid >> 6;
  const int wy = wid >> 1, wx = wid & 1;
  const int lrow = l & 15, lkb = (l >> 4) * 8;

  f32x4 acck[4][4] = {}, accv[4][4] = {};

  for (int k0 = 0; k0 < CC; k0 += 32) {
    {
      int r = tid >> 3, c = (tid & 7) * 4;
#pragma unroll
      for (int p = 0; p < 4; ++p, r += 32) {
        float4v v = *(const float4v*)(A + (size_t)(m0 + r) * CC + k0 + c);
        float4v wk = *(const float4v*)(Wk + (size_t)(n0 + r) * CC + k0 + c);
        float4v wv = *(const float4v*)(Wv + (size_t)(n0 + r) * CC + k0 + c);
#pragma unroll
        for (int i = 0; i < 4; ++i) {
          unsigned short h = bf16_rn(v[i]);
          Ah[r][c + i] = h;
          Al[r][c + i] = bf16_rn(v[i] - bf16_tof(h));
          unsigned short hk = bf16_rn(wk[i]);
          Bkh[r][c + i] = hk;
          Bkl[r][c + i] = bf16_rn(wk[i] - bf16_tof(hk));
          Bvh[r][c + i] = bf16_rn(wv[i]);
        }
      }
    }
    __syncthreads();

    bf16x8 ah[4], al[4], bkh[4], bkl[4], bvh[4];
#pragma unroll
    for (int mf = 0; mf < 4; ++mf) {
      ah[mf] = *(const bf16x8*)&Ah[wy * 64 + mf * 16 + lrow][lkb];
      al[mf] = *(const bf16x8*)&Al[wy * 64 + mf * 16 + lrow][lkb];
    }
#pragma unroll
    for (int nf = 0; nf < 4; ++nf) {
      bkh[nf] = *(const bf16x8*)&Bkh[wx * 64 + nf * 16 + lrow][lkb];
      bkl[nf] = *(const bf16x8*)&Bkl[wx * 64 + nf * 16 + lrow][lkb];
      bvh[nf] = *(const bf16x8*)&Bvh[wx * 64 + nf * 16 + lrow][lkb];
    }
#pragma unroll
    for (int mf = 0; mf < 4; ++mf)
#pragma unroll
      for (int nf = 0; nf < 4; ++nf) {
        acck[mf][nf] =
            __builtin_amdgcn_mfma_f32_16x16x32_bf16(ah[mf], bkh[nf], acck[mf][nf], 0, 0, 0);
        acck[mf][nf] =
            __builtin_amdgcn_mfma_f32_16x16x32_bf16(ah[mf], bkl[nf], acck[mf][nf], 0, 0, 0);
        acck[mf][nf] =
            __builtin_amdgcn_mfma_f32_16x16x32_bf16(al[mf], bkh[nf], acck[mf][nf], 0, 0, 0);
        accv[mf][nf] =
            __builtin_amdgcn_mfma_f32_16x16x32_bf16(ah[mf], bvh[nf], accv[mf][nf], 0, 0, 0);
      }
    __syncthreads();
  }

#pragma unroll
  for (int mf = 0; mf < 4; ++mf)
#pragma unroll
    for (int r = 0; r < 4; ++r) {
      int m = m0 + wy * 64 + mf * 16 + (l >> 4) * 4 + r;
#pragma unroll
      for (int nf = 0; nf < 4; ++nf) {
        int n = n0 + wx * 64 + nf * 16 + lrow;
        size_t off = ((size_t)b * TT + m) * CC + n;
        kout[off] = acck[mf][nf][r];
        vout[off] = bf16_rn(accv[mf][nf][r]);
      }
    }
}

// ---------------------------------------------------------------------------
// sim (bf16-split MFMA, no store) + per-block per-token top-3 candidates.
// ---------------------------------------------------------------------------
__global__ __launch_bounds__(256) void mfma_sim_top3(
    const float* __restrict__ q, const float* __restrict__ kb,
    unsigned long long* __restrict__ cand1, unsigned long long* __restrict__ cand2,
    unsigned long long* __restrict__ cand3) {
  __shared__ unsigned short Ah[128][40], Al[128][40], Bh[128][40], Bl[128][40];
  __shared__ unsigned long long c1[128], c2[128], c3[128];

  const int b = blockIdx.z;
  const float* A = q + (size_t)b * NNODE * CC;
  const float* Bm = kb + (size_t)b * TT * CC;
  const int n0 = blockIdx.y * 128;  // nodes
  const int t0 = blockIdx.x * 128;  // tokens
  const int tid = threadIdx.x;
  const int l = tid & 63;
  const int wid = tid >> 6;
  const int wy = wid >> 1, wx = wid & 1;
  const int lrow = l & 15, lkb = (l >> 4) * 8;

  if (tid < 128) { c1[tid] = 0ULL; c2[tid] = 0ULL; c3[tid] = 0ULL; }

  f32x4 acc[4][4] = {};

  for (int k0 = 0; k0 < CC; k0 += 32) {
    {
      int r = tid >> 3, c = (tid & 7) * 4;
#pragma unroll
      for (int p = 0; p < 4; ++p, r += 32) {
        float4v v = *(const float4v*)(A + (size_t)(n0 + r) * CC + k0 + c);
        float4v w = *(const float4v*)(Bm + (size_t)(t0 + r) * CC + k0 + c);
#pragma unroll
        for (int i = 0; i < 4; ++i) {
          unsigned short h = bf16_rn(v[i]);
          Ah[r][c + i] = h;
          Al[r][c + i] = bf16_rn(v[i] - bf16_tof(h));
          unsigned short hb = bf16_rn(w[i]);
          Bh[r][c + i] = hb;
          Bl[r][c + i] = bf16_rn(w[i] - bf16_tof(hb));
        }
      }
    }
    __syncthreads();

    bf16x8 ah[4], al[4], bh[4], bl[4];
#pragma unroll
    for (int mf = 0; mf < 4; ++mf) {
      ah[mf] = *(const bf16x8*)&Ah[wy * 64 + mf * 16 + lrow][lkb];
      al[mf] = *(const bf16x8*)&Al[wy * 64 + mf * 16 + lrow][lkb];
    }
#pragma unroll
    for (int nf = 0; nf < 4; ++nf) {
      bh[nf] = *(const bf16x8*)&Bh[wx * 64 + nf * 16 + lrow][lkb];
      bl[nf] = *(const bf16x8*)&Bl[wx * 64 + nf * 16 + lrow][lkb];
    }
#pragma unroll
    for (int mf = 0; mf < 4; ++mf)
#pragma unroll
      for (int nf = 0; nf < 4; ++nf) {
        acc[mf][nf] =
            __builtin_amdgcn_mfma_f32_16x16x32_bf16(ah[mf], bh[nf], acc[mf][nf], 0, 0, 0);
        acc[mf][nf] =
            __builtin_amdgcn_mfma_f32_16x16x32_bf16(ah[mf], bl[nf], acc[mf][nf], 0, 0, 0);
        acc[mf][nf] =
            __builtin_amdgcn_mfma_f32_16x16x32_bf16(al[mf], bh[nf], acc[mf][nf], 0, 0, 0);
      }
    __syncthreads();
  }

  const float scl = 0.04419417382415922f;
#pragma unroll
  for (int nf = 0; nf < 4; ++nf) {
    int tcol = wx * 64 + nf * 16 + lrow;
    unsigned long long m = 0ULL;
#pragma unroll
    for (int mf = 0; mf < 4; ++mf)
#pragma unroll
      for (int r = 0; r < 4; ++r) {
        unsigned node = (unsigned)(n0 + wy * 64 + mf * 16 + (l >> 4) * 4 + r);
        unsigned long long pk =
            ((unsigned long long)fkey(acc[mf][nf][r] * scl) << 32) | node;
        if (pk > m) m = pk;
      }
    atomicMax(&c1[tcol], m);
  }
  __syncthreads();
#pragma unroll
  for (int nf = 0; nf < 4; ++nf) {
    int tcol = wx * 64 + nf * 16 + lrow;
    unsigned w1 = (unsigned)c1[tcol];
    unsigned long long m = 0ULL;
#pragma unroll
    for (int mf = 0; mf < 4; ++mf)
#pragma unroll
      for (int r = 0; r < 4; ++r) {
        unsigned node = (unsigned)(n0 + wy * 64 + mf * 16 + (l >> 4) * 4 + r);
        if (node == w1) continue;
        unsigned long long pk =
            ((unsigned long long)fkey(acc[mf][nf][r] * scl) << 32) | node;
        if (pk > m) m = pk;
      }
    if (m) atomicMax(&c2[tcol], m);
  }
  __syncthreads();
#pragma unroll
  for (int nf = 0; nf < 4; ++nf) {
    int tcol = wx * 64 + nf * 16 + lrow;
    unsigned w1 = (unsigned)c1[tcol];
    unsigned w2 = (unsigned)c2[tcol];
    unsigned long long m = 0ULL;
#pragma unroll
    for (int mf = 0; mf < 4; ++mf)
#pragma unroll
      for (int r = 0; r < 4; ++r) {
        unsigned node = (unsigned)(n0 + wy * 64 + mf * 16 + (l >> 4) * 4 + r);
        if (node == w1 || node == w2) continue;
        unsigned long long pk =
            ((unsigned long long)fkey(acc[mf][nf][r] * scl) << 32) | node;
        if (pk > m) m = pk;
      }
    if (m) atomicMax(&c3[tcol], m);
  }
  __syncthreads();
  if (tid < 128) {
    size_t base = ((size_t)b * TT + (t0 + tid)) * 8 + blockIdx.y;
    cand1[base] = c1[tid];
    cand2[base] = c2[tid];
    cand3[base] = c3[tid];
  }
}

__global__ __launch_bounds__(256) void fill_zero(unsigned* __restrict__ p, long long n) {
  long long i = (long long)blockIdx.x * 256 + threadIdx.x;
  long long stride = (long long)gridDim.x * 256;
  for (; i < n; i += stride) p[i] = 0u;
}

// ---------------------------------------------------------------------------
// Merge 8x(top-3) -> global top1 + rivals within GAP_MARGIN -> flag lists.
// ---------------------------------------------------------------------------
__global__ __launch_bounds__(256) void merge_flag_kernel(
    const unsigned long long* __restrict__ cand1,
    const unsigned long long* __restrict__ cand2,
    const unsigned long long* __restrict__ cand3,
    unsigned long long* __restrict__ amaxIdx,
    unsigned* __restrict__ counts, unsigned* __restrict__ flaglist,
    unsigned* __restrict__ clist) {
  int bt = blockIdx.x * 256 + threadIdx.x;  // [0, B*T)
  int b = bt >> 11;
  unsigned long long best = 0ULL;
#pragma unroll
  for (int nb = 0; nb < 8; ++nb) {
    unsigned long long v = cand1[(size_t)bt * 8 + nb];
    if (v > best) best = v;
  }
  amaxIdx[bt] = best;
  float v1 = fdec((unsigned)(best >> 32));
  float thr = v1 - GAP_MARGIN;
  unsigned bestnode = (unsigned)best;

  unsigned nodes[MAXC];
  int cnt = 0;
#pragma unroll
  for (int nb = 0; nb < 8; ++nb) {
    unsigned long long cs[3] = {cand1[(size_t)bt * 8 + nb], cand2[(size_t)bt * 8 + nb],
                                cand3[(size_t)bt * 8 + nb]};
#pragma unroll
    for (int s = 0; s < 3; ++s) {
      float v = fdec((unsigned)(cs[s] >> 32));
      unsigned nd = (unsigned)cs[s];
      if (v >= thr && nd != bestnode && cnt < MAXC) nodes[cnt++] = nd;
    }
  }
  if (cnt > 0) {
    unsigned p = atomicAdd(&counts[b], 1u);
    flaglist[b * TT + p] = (unsigned)bt;
    clist[(size_t)bt * 8] = (unsigned)(cnt + 1);
    clist[(size_t)bt * 8 + 1] = bestnode;
    for (int i = 0; i < cnt; ++i) clist[(size_t)bt * 8 + 2 + i] = nodes[i];
  }
}

// ---------------------------------------------------------------------------
// Exact f64 recheck, WAVE-COOPERATIVE + COALESCED (one kernel).
// Grid (16 flag-slots, B). Per flag:
//   k64[d] = Wk[d,:].x_t     (wave-per-row, lanes over c -> coalesced, shfl-reduce)
//   z[t']  = x[t',:].k64     (wave-per-row, 2 rows in flight, coalesced)
//   sim64(n) = Wq[n,:].z + bq[n]*sum(k64)  (candidates only, block-reduce)
// Identical math to validated round-9/10 recheck (only f64 sum order differs).
// ---------------------------------------------------------------------------
__global__ __launch_bounds__(256) void recheck_kernel(
    const float* __restrict__ x, const float* __restrict__ Wq,
    const float* __restrict__ bq, const float* __restrict__ Wk,
    const unsigned* __restrict__ counts, const unsigned* __restrict__ flaglist,
    const unsigned* __restrict__ clist, unsigned long long* __restrict__ amaxIdx) {
  __shared__ float xs[CC];    // 2 KB
  __shared__ double k64[CC];  // 4 KB
  __shared__ float zs[TT];    // 8 KB
  __shared__ double red[4];

  const int b = blockIdx.y;
  const unsigned cnt = counts[b];
  const int tid = threadIdx.x;
  const int lane = tid & 63;
  const int wv = tid >> 6;  // 4 waves
  const float* xb = x + (size_t)b * TT * CC;

  for (unsigned fi = blockIdx.x; fi < cnt; fi += 16) {
    unsigned bt = flaglist[b * TT + fi];
    int t = bt & (TT - 1);
    for (int c = tid; c < CC; c += 256) xs[c] = xb[(size_t)t * CC + c];
    __syncthreads();

    // k64: wave per row pair (d0, d0+4); lanes over c (coalesced)
    for (int d0 = wv; d0 < CC; d0 += 8) {
      int d1 = d0 + 4;
      const float* w0 = Wk + (size_t)d0 * CC;
      const float* w1 = Wk + (size_t)d1 * CC;
      double a0 = 0.0, a1 = 0.0;
#pragma unroll
      for (int i = 0; i < CC / 64; ++i) {
        double xv = (double)xs[lane + i * 64];
        a0 = fma((double)w0[lane + i * 64], xv, a0);
        a1 = fma((double)w1[lane + i * 64], xv, a1);
      }
#pragma unroll
      for (int off = 32; off > 0; off >>= 1) {
        a0 += __shfl_down(a0, off, 64);
        a1 += __shfl_down(a1, off, 64);
      }
      if (lane == 0) { k64[d0] = a0; k64[d1] = a1; }
    }
    __syncthreads();

    // ssum = sum(k64), block-reduce
    double ps = k64[tid] + k64[tid + 256];
#pragma unroll
    for (int off = 32; off > 0; off >>= 1) ps += __shfl_down(ps, off, 64);
    if ((tid & 63) == 0) red[tid >> 6] = ps;
    __syncthreads();
    const double ssum = red[0] + red[1] + red[2] + red[3];
    __syncthreads();

    // z: wave per row pair (tp0, tp0+4); lanes over c (coalesced)
    for (int tp0 = wv; tp0 < TT; tp0 += 8) {
      int tp1 = tp0 + 4;
      const float* x0 = xb + (size_t)tp0 * CC;
      const float* x1 = xb + (size_t)tp1 * CC;
      double a0 = 0.0, a1 = 0.0;
#pragma unroll
      for (int i = 0; i < CC / 64; ++i) {
        double kk = k64[lane + i * 64];
        a0 = fma((double)x0[lane + i * 64], kk, a0);
        a1 = fma((double)x1[lane + i * 64], kk, a1);
      }
#pragma unroll
      for (int off = 32; off > 0; off >>= 1) {
        a0 += __shfl_down(a0, off, 64);
        a1 += __shfl_down(a1, off, 64);
      }
      if (lane == 0) { zs[tp0] = (float)a0; zs[tp1] = (float)a1; }
    }
    __syncthreads();

    // candidates: sim64(n) = Wq[n,:].z + bq[n]*ssum
    const double scl = 0.04419417382415922;
    unsigned ncand = clist[(size_t)bt * 8];
    unsigned long long bestpk = 0ULL;
    double bestv = -1e300;
    for (unsigned ci = 0; ci < ncand; ++ci) {
      unsigned n = clist[(size_t)bt * 8 + 1 + ci];
      const float* wq = Wq + (size_t)n * TT;
      double a = 0.0;
#pragma unroll
      for (int i = 0; i < TT / 256; ++i) {
        int tp = tid + i * 256;
        a = fma((double)wq[tp], (double)zs[tp], a);
      }
#pragma unroll
      for (int off = 32; off > 0; off >>= 1) a += __shfl_down(a, off, 64);
      if ((tid & 63) == 0) red[tid >> 6] = a;
      __syncthreads();
      double s = (red[0] + red[1] + red[2] + red[3]) + (double)bq[n] * ssum;
      if (s > bestv) {
        bestv = s;
        bestpk = ((unsigned long long)fkey((float)(s * scl)) << 32) | n;
      }
      __syncthreads();
    }
    if (tid == 0) amaxIdx[bt] = bestpk;
    __syncthreads();
  }
}

__global__ __launch_bounds__(256) void node_max_kernel(
    const unsigned long long* __restrict__ amaxIdx, unsigned* __restrict__ Mpack) {
  int i = blockIdx.x * 256 + threadIdx.x;
  unsigned long long pk = amaxIdx[i];
  int b = i >> 11;
  unsigned w = (unsigned)pk;
  atomicMax(&Mpack[b * NNODE + w], (unsigned)(pk >> 32));
}

__global__ __launch_bounds__(256) void node_denom_kernel(
    const unsigned long long* __restrict__ amaxIdx, const unsigned* __restrict__ Mpack,
    float* __restrict__ D, float* __restrict__ att_val) {
  int i = blockIdx.x * 256 + threadIdx.x;
  unsigned long long pk = amaxIdx[i];
  int b = i >> 11;
  unsigned w = (unsigned)pk;
  float amaxf = fdec((unsigned)(pk >> 32));
  float Mf = fdec(Mpack[b * NNODE + w]);
  float e = expf(amaxf - Mf);
  att_val[i] = e;
  atomicAdd(&D[b * NNODE + w], e);
}

__global__ __launch_bounds__(256) void att_write_kernel(
    const unsigned long long* __restrict__ amaxIdx, const float* __restrict__ D,
    float* __restrict__ att_val, float* __restrict__ att_out) {
  int i = blockIdx.x * 256 + threadIdx.x;
  unsigned long long pk = amaxIdx[i];
  int b = i >> 11;
  int t = i & (TT - 1);
  unsigned w = (unsigned)pk;
  float a = att_val[i] / D[b * NNODE + w];
  att_val[i] = a;
  att_out[((size_t)b * NNODE + w) * TT + t] = a;
}

__global__ __launch_bounds__(256) void pv_scatter_kernel(
    const unsigned long long* __restrict__ amaxIdx, const float* __restrict__ att_val,
    const unsigned short* __restrict__ v, float* __restrict__ out0) {
  int bt = blockIdx.x;  // [0, B*T)
  int b = bt >> 11;
  float a = att_val[bt];
  unsigned w = (unsigned)amaxIdx[bt];
  const unsigned short* vr = v + (size_t)bt * CC;
  float* orow = out0 + ((size_t)b * NNODE + w) * CC;
  for (int c = threadIdx.x; c < CC; c += 256)
    atomicAdd(&orow[c], a * bf16_tof(vr[c]));
}

extern "C" void kernel_launch(void* const* d_in, const int* in_sizes, int n_in,
                              void* d_out, int out_size, void* d_ws, size_t ws_size,
                              hipStream_t stream) {
  const float* x = (const float*)d_in[0];     // [B,T,C]  f32
  const float* Wq = (const float*)d_in[1];    // [N,T]
  const float* bq = (const float*)d_in[2];    // [N]
  const float* Wk = (const float*)d_in[3];    // [C,C]
  const float* Wv = (const float*)d_in[4];    // [C,C]
  const float* Wout = (const float*)d_in[5];  // [C,C]
  const float* bout = (const float*)d_in[6];  // [C]

  float* out = (float*)d_out;                      // [B,N,C] f32
  float* att_out = out + (size_t)BB * NNODE * CC;  // [B,N,T] f32

  // Workspace layout (f32 word units), ~72 MB total.
  float* ws = (float*)d_ws;
  float* q = ws;                                // B*N*C f32 (reused as out0)
  float* kbuf = q + (size_t)BB * NNODE * CC;    // B*T*C f32
  unsigned short* vbuf = (unsigned short*)(kbuf + (size_t)BB * TT * CC);  // bf16 bits
  unsigned long long* cand1 =
      (unsigned long long*)((unsigned*)vbuf + (size_t)BB * TT * CC / 2);  // B*T*8 u64
  unsigned long long* cand2 = cand1 + (size_t)BB * TT * 8;
  unsigned long long* cand3 = cand2 + (size_t)BB * TT * 8;
  unsigned long long* amaxIdx = cand3 + (size_t)BB * TT * 8;              // B*T u64
  unsigned* Mpack = (unsigned*)(amaxIdx + (size_t)BB * TT);               // B*N u32
  float* D = (float*)(Mpack + (size_t)BB * NNODE);                        // B*N f32
  unsigned* counts = (unsigned*)(D + (size_t)BB * NNODE);                 // 16 u32
  float* att_val = (float*)(counts + 16);                                 // B*T f32
  unsigned* flaglist = (unsigned*)(att_val + (size_t)BB * TT);            // B*T u32
  unsigned* clist = flaglist + (size_t)BB * TT;                           // B*T*8 u32
  float* out0 = q;

  dim3 blk(256);

  // Z1: zero Mpack | D | counts (contiguous)
  fill_zero<<<dim3(64), blk, 0, stream>>>(Mpack, (long long)BB * NNODE * 2 + 16);
  // Z2: zero att region of d_out
  fill_zero<<<dim3(4096), blk, 0, stream>>>((unsigned*)att_out,
                                            (long long)BB * NNODE * TT);

  // q[b,n,c] = sum_t Wq[n,t] x[b,t,c] + bq[n]  (bf16-split MFMA)
  mfma_gemm<true, false, 1><<<dim3(CC / 128, NNODE / 128, BB), blk, 0, stream>>>(
      Wq, x, q, bq, TT, TT, CC, CC, 0LL, (long long)TT * CC,
      (long long)NNODE * CC, 1.0f);

  // fused k (split, f32) + v (plain, bf16)
  mfma_kv<<<dim3(CC / 128, TT / 128, BB), blk, 0, stream>>>(x, Wk, Wv, kbuf, vbuf);

  // sim (split MFMA) + per-block top-3 candidates
  mfma_sim_top3<<<dim3(TT / 128, NNODE / 128, BB), blk, 0, stream>>>(
      q, kbuf, cand1, cand2, cand3);

  // merge -> amaxIdx + flagged-token candidate lists
  merge_flag_kernel<<<dim3(BB * TT / 256), blk, 0, stream>>>(
      cand1, cand2, cand3, amaxIdx, counts, flaglist, clist);

  // exact f64 recheck (wave-cooperative, coalesced)
  recheck_kernel<<<dim3(16, BB), blk, 0, stream>>>(
      x, Wq, bq, Wk, counts, flaglist, clist, amaxIdx);

  // zero out0 (aliases q; q dead after sim)
  fill_zero<<<dim3(2048), blk, 0, stream>>>((unsigned*)out0, (long long)BB * NNODE * CC);

  node_max_kernel<<<dim3(BB * TT / 256), blk, 0, stream>>>(amaxIdx, Mpack);
  node_denom_kernel<<<dim3(BB * TT / 256), blk, 0, stream>>>(amaxIdx, Mpack, D, att_val);
  att_write_kernel<<<dim3(BB * TT / 256), blk, 0, stream>>>(amaxIdx, D, att_val, att_out);

  // sparse PV scatter: out0[b,w,c] += att * v[b,t,c]
  pv_scatter_kernel<<<dim3(BB * TT), blk, 0, stream>>>(amaxIdx, att_val, vbuf, out0);

  // out[b,n,d] = sum_c out0[b,n,c] Wout[d,c] + bout[d]  (plain MFMA, flattened M)
  mfma_gemm<false, true, 2><<<dim3(CC / 128, BB * NNODE / 128, 1), blk, 0, stream>>>(
      out0, Wout, out, bout, CC, CC, CC, CC, 0LL, 0LL, 0LL, 1.0f);
}